// Round 10
// baseline (301.972 us; speedup 1.0000x reference)
//
#include <hip/hip_runtime.h>
#include <hip/hip_bf16.h>

#define NHEAD 16
#define DHEAD 64
#define DMODEL 1024
#define QLEN 1024
#define MEMLEN 1024
#define BSZ 2
#define KLEN 2048
#define LN_EPS 1e-5f

typedef __hip_bfloat16 bf16;
typedef __attribute__((ext_vector_type(8))) short short8;
typedef __attribute__((ext_vector_type(4))) float f32x4;

__device__ __forceinline__ float b2f(bf16 x) { return __bfloat162float(x); }
__device__ __forceinline__ bf16 f2b(float x) { return __float2bfloat16(x); }
__device__ __forceinline__ short f2bs(float f) {
    bf16 h = __float2bfloat16(f);
    return *reinterpret_cast<short*>(&h);
}
__device__ __forceinline__ float s2f(short s) {
    bf16 h = *reinterpret_cast<bf16*>(&s);
    return __bfloat162float(h);
}

#define MFMA16(a, b, c) __builtin_amdgcn_mfma_f32_16x16x32_bf16(a, b, c, 0, 0, 0)

#define AS1 __attribute__((address_space(1)))
#define AS3 __attribute__((address_space(3)))
// async global->LDS, 16B/lane; LDS dest = wave-uniform base + lane*16
__device__ __forceinline__ void gld16(const bf16* g, bf16* l) {
    __builtin_amdgcn_global_load_lds((const AS1 void*)(uintptr_t)g,
                                     (AS3 void*)(uint32_t)(uintptr_t)l, 16, 0, 0);
}

// ---------------- f32 -> bf16 flat convert ----------------
__global__ __launch_bounds__(256)
void conv_bf16(const float* __restrict__ src, bf16* __restrict__ dst, int n4) {
    int i = blockIdx.x * 256 + threadIdx.x;
    if (i < n4) {
        const float4 v = reinterpret_cast<const float4*>(src)[i];
        bf16 o[4] = {f2b(v.x), f2b(v.y), f2b(v.z), f2b(v.w)};
        reinterpret_cast<ulong1*>(dst)[i] = *reinterpret_cast<ulong1*>(o);
    }
}

// ---------------- f32 [K][N] -> bf16 [N][K] transpose-convert ----------------
__global__ __launch_bounds__(256)
void conv_wT(const float* __restrict__ in, bf16* __restrict__ out, int K, int N) {
    __shared__ bf16 T[64][65];
    const int n0 = blockIdx.x * 64, k0 = blockIdx.y * 64;
    const int t = threadIdx.x;
    #pragma unroll
    for (int e = 0; e < 16; e++) {
        int flat = e * 256 + t;
        int kl = flat >> 6, nl = flat & 63;
        T[kl][nl] = f2b(in[(size_t)(k0 + kl) * N + n0 + nl]);
    }
    __syncthreads();
    #pragma unroll
    for (int e = 0; e < 16; e++) {
        int flat = e * 256 + t;
        int nl = flat >> 6, kl = flat & 63;
        out[(size_t)(n0 + nl) * K + k0 + kl] = T[kl][nl];
    }
}

// ---------------- MFMA GEMM (m97 staging): C = A[M,K] @ Bt[N,K]^T ----------------
// 128x128 tile, BK=32. Staging via global_load_lds width-16 into unpadded
// [128][32] LDS (DMA order = lane order). 4 waves 2x2, each 64x64.
__global__ __launch_bounds__(256)
void gemm_mfma(const bf16* __restrict__ A, const bf16* __restrict__ Bt,
               int M, int N, int K, int mode,
               const float* __restrict__ rwb, const float* __restrict__ rrb,
               bf16* __restrict__ Qw, bf16* __restrict__ Qr,
               bf16* __restrict__ Kb, bf16* __restrict__ Vb,
               bf16* __restrict__ Cb, float* __restrict__ Cf) {
    const int bm = blockIdx.x * 128, bn = blockIdx.y * 128;
    if (mode == 0 && bm < 2048 && bn < 1024) return;  // Q of mem rows: never used
    __shared__ bf16 As[128 * 32];
    __shared__ bf16 Bs[128 * 32];
    const int t = threadIdx.x;
    const int w = t >> 6, lane = t & 63, quad = lane >> 4, l16 = lane & 15;
    const int wm = (w >> 1) * 64, wn = (w & 1) * 64;
    const int lrow = lane >> 2, lcol = (lane & 3) * 8;

    f32x4 acc[4][4];
    #pragma unroll
    for (int mt = 0; mt < 4; mt++)
        #pragma unroll
        for (int nt = 0; nt < 4; nt++) acc[mt][nt] = (f32x4){0.f, 0.f, 0.f, 0.f};

    for (int k0 = 0; k0 < K; k0 += 32) {
        #pragma unroll
        for (int e = 0; e < 2; e++) {
            int ch = w + 4 * e;                       // 0..7, wave-uniform
            int row = ch * 16 + lrow;
            gld16(A  + (size_t)(bm + row) * K + k0 + lcol, As + ch * 512);
            gld16(Bt + (size_t)(bn + row) * K + k0 + lcol, Bs + ch * 512);
        }
        __syncthreads();
        short8 af[4], bfr[4];
        #pragma unroll
        for (int mt = 0; mt < 4; mt++)
            af[mt] = *reinterpret_cast<short8*>(&As[(wm + 16 * mt + l16) * 32 + quad * 8]);
        #pragma unroll
        for (int nt = 0; nt < 4; nt++)
            bfr[nt] = *reinterpret_cast<short8*>(&Bs[(wn + 16 * nt + l16) * 32 + quad * 8]);
        #pragma unroll
        for (int mt = 0; mt < 4; mt++)
            #pragma unroll
            for (int nt = 0; nt < 4; nt++)
                acc[mt][nt] = MFMA16(af[mt], bfr[nt], acc[mt][nt]);
        __syncthreads();
    }

    #pragma unroll
    for (int mt = 0; mt < 4; mt++)
        #pragma unroll
        for (int nt = 0; nt < 4; nt++)
            #pragma unroll
            for (int r = 0; r < 4; r++) {
                int m = bm + wm + 16 * mt + quad * 4 + r;
                int c = bn + wn + 16 * nt + l16;
                float v = acc[mt][nt][r];
                if (mode == 0) {
                    int seg = c >> 10, cc = c & 1023;
                    if (seg == 0) {
                        if (m >= 2048) {
                            size_t o = (size_t)(m - 2048) * 1024 + cc;
                            Qw[o] = f2b(v + rwb[cc]);
                            Qr[o] = f2b(v + rrb[cc]);
                        }
                    } else if (seg == 1) Kb[(size_t)m * 1024 + cc] = f2b(v);
                    else                 Vb[(size_t)m * 1024 + cc] = f2b(v);
                } else if (mode == 1) Cb[(size_t)m * N + c] = f2b(v);
                else                  Cf[(size_t)m * N + c] = v;
            }
}

// ---------------- V transpose: Vb[j*2+b][d] -> Vt[(d*2+b)][j] ----------------
__global__ __launch_bounds__(256)
void transpose_v(const bf16* __restrict__ Vb, bf16* __restrict__ Vt) {
    __shared__ bf16 T[64][65];
    const int J0 = blockIdx.x * 64, D0 = blockIdx.y * 64, b = blockIdx.z;
    const int t = threadIdx.x;
    #pragma unroll
    for (int e = 0; e < 16; e++) {
        int flat = e * 256 + t;
        int jl = flat >> 6, dl = flat & 63;
        T[jl][dl] = Vb[(size_t)((J0 + jl) * 2 + b) * 1024 + D0 + dl];
    }
    __syncthreads();
    #pragma unroll
    for (int e = 0; e < 16; e++) {
        int flat = e * 256 + t;
        int dl = flat >> 6, jl = flat & 63;
        Vt[(size_t)((D0 + dl) * 2 + b) * 2048 + J0 + jl] = T[jl][dl];
    }
}

// ---------------- MFMA flash attention, LDS-staged, split-J partials ----------------
// 256 threads = 4 waves; block = 64 q-rows, half the J range (js). LDS 51KB ->
// 3 blocks/CU. Grid 1024 = 8 xcd * (4 pairs * 16 i0 * 2 js), pair pinned per XCD.
__global__ __launch_bounds__(256, 3)
void attn_mfma(const bf16* __restrict__ Qw, const bf16* __restrict__ Qr,
               const bf16* __restrict__ Kb, const bf16* __restrict__ Vt,
               const bf16* __restrict__ Rk, bf16* __restrict__ Po,
               float* __restrict__ ml) {
    const int id = blockIdx.x;
    const int xcd = id & 7, local = id >> 3;          // local 0..127
    const int pair = xcd * 4 + (local & 3);           // 0..31
    const int i0 = (local >> 2) & 15;
    const int js = local >> 6;                        // j-chunk 0/1
    const int b = pair & 1, n = pair >> 1;
    const int I0 = i0 * 64;

    const int tid = threadIdx.x;
    const int w = tid >> 6, lane = tid & 63;
    const int quad = lane >> 4, l16 = lane & 15;
    const int qbase = I0 + 16 * w;
    const int ln8 = lane >> 3;
    const int cs = (lane & 7) ^ (ln8 & 7);            // swizzled source chunk
    const int q0 = (quad ^ (l16 & 7)) * 8;            // frag chunk (k 0..31)
    const int q1 = q0 ^ 32;

    __shared__ bf16 Ks[64 * 64];
    __shared__ bf16 Vs[64 * 64];
    __shared__ bf16 Rs[128 * 64];
    __shared__ short WlB_s[4][16 * 80];   // rel-shift window, bf16
    __shared__ short Pb_s[4][16 * 72];
    short* WlB = WlB_s[w];
    short* Pb = Pb_s[w];

    short8 aqw[2], aqr[2];
    {
        const bf16* qp = Qw + ((size_t)(qbase + l16) * 2 + b) * 1024 + n * 64 + quad * 8;
        aqw[0] = *reinterpret_cast<const short8*>(qp);
        aqw[1] = *reinterpret_cast<const short8*>(qp + 32);
        const bf16* qp2 = Qr + ((size_t)(qbase + l16) * 2 + b) * 1024 + n * 64 + quad * 8;
        aqr[0] = *reinterpret_cast<const short8*>(qp2);
        aqr[1] = *reinterpret_cast<const short8*>(qp2 + 32);
    }

    f32x4 O[4];
    #pragma unroll
    for (int d = 0; d < 4; d++) O[d] = (f32x4){0.f, 0.f, 0.f, 0.f};
    float m_run = -1e30f;
    float pl[4] = {0.f, 0.f, 0.f, 0.f};

    const int T = i0 + 17;
    const int t0 = js ? (T >> 1) : 0;
    const int t1 = js ? T : (T >> 1);
    const int koff = b * 1024 + n * 64 + cs * 8;
    const size_t voff = (size_t)n * 262144 + b * 2048 + cs * 8;
    const int rcol = n * 64 + cs * 8;
    const int rbl = 48 - 16 * w;

    for (int tt = t0; tt < t1; tt++) {
        const int J0 = tt * 64;
        const int RU0 = J0 - I0 + 960;

        #pragma unroll
        for (int e = 0; e < 2; e++) {
            int ch = w + 4 * e;
            int krow = J0 + ch * 8 + ln8;
            gld16(Kb + (size_t)krow * 2048 + koff, Ks + ch * 512);
            int dl = ch * 8 + ln8;
            gld16(Vt + (size_t)dl * 4096 + voff + J0, Vs + ch * 512);
        }
        #pragma unroll
        for (int e = 0; e < 4; e++) {
            int ch = w + 4 * e;
            int rrow = RU0 + ch * 8 + ln8;
            rrow = min(rrow, 2047);                   // OOB rows hit only masked pairs
            gld16(Rk + (size_t)rrow * 1024 + rcol, Rs + ch * 512);
        }
        __syncthreads();

        // ---- BD window GEMM from Rs ----
        #pragma unroll
        for (int s = 0; s < 5; s++) {
            int rl = rbl + 16 * s + l16;
            short8 b0 = *reinterpret_cast<short8*>(&Rs[rl * 64 + q0]);
            short8 b1 = *reinterpret_cast<short8*>(&Rs[rl * 64 + q1]);
            f32x4 acc = (f32x4){0.f, 0.f, 0.f, 0.f};
            acc = MFMA16(aqr[0], b0, acc);
            acc = MFMA16(aqr[1], b1, acc);
            #pragma unroll
            for (int r = 0; r < 4; r++)
                WlB[(quad * 4 + r) * 80 + 16 * s + l16] = f2bs(acc[r]);
        }

        // ---- AC GEMM from Ks + score assembly ----
        float sv[4][4];
        #pragma unroll
        for (int n16 = 0; n16 < 4; n16++) {
            int kr = 16 * n16 + l16;
            short8 k0 = *reinterpret_cast<short8*>(&Ks[kr * 64 + q0]);
            short8 k1 = *reinterpret_cast<short8*>(&Ks[kr * 64 + q1]);
            f32x4 acc = (f32x4){0.f, 0.f, 0.f, 0.f};
            acc = MFMA16(aqw[0], k0, acc);
            acc = MFMA16(aqw[1], k1, acc);
            #pragma unroll
            for (int r = 0; r < 4; r++) {
                int row = quad * 4 + r, col = 16 * n16 + l16;
                float s = (acc[r] + s2f(WlB[row * 80 + col - row + 15])) * 0.125f;
                if (J0 + col > qbase + row + MEMLEN) s = -1e30f;
                sv[n16][r] = s;
            }
        }

        // ---- online softmax (shared per-quad max) ----
        float mx = sv[0][0];
        #pragma unroll
        for (int n16 = 0; n16 < 4; n16++)
            #pragma unroll
            for (int r = 0; r < 4; r++) mx = fmaxf(mx, sv[n16][r]);
        #pragma unroll
        for (int msk = 1; msk < 16; msk <<= 1) mx = fmaxf(mx, __shfl_xor(mx, msk));
        const float mn = fmaxf(m_run, mx);
        const float alpha = __expf(m_run - mn);
        m_run = mn;
        #pragma unroll
        for (int n16 = 0; n16 < 4; n16++)
            #pragma unroll
            for (int r = 0; r < 4; r++) sv[n16][r] = __expf(sv[n16][r] - mn);
        #pragma unroll
        for (int r = 0; r < 4; r++)
            pl[r] = pl[r] * alpha + (sv[0][r] + sv[1][r] + sv[2][r] + sv[3][r]);
        #pragma unroll
        for (int d = 0; d < 4; d++)
            #pragma unroll
            for (int r = 0; r < 4; r++) O[d][r] *= alpha;

        // ---- P -> LDS bf16 (C-layout), read back as A-frags ----
        #pragma unroll
        for (int n16 = 0; n16 < 4; n16++)
            #pragma unroll
            for (int r = 0; r < 4; r++)
                Pb[(quad * 4 + r) * 72 + 16 * n16 + l16] = f2bs(sv[n16][r]);
        short8 ap0 = *reinterpret_cast<short8*>(&Pb[l16 * 72 + quad * 8]);
        short8 ap1 = *reinterpret_cast<short8*>(&Pb[l16 * 72 + 32 + quad * 8]);

        // ---- PV from Vs ----
        #pragma unroll
        for (int ds = 0; ds < 4; ds++) {
            int dr = 16 * ds + l16;
            short8 v0 = *reinterpret_cast<short8*>(&Vs[dr * 64 + q0]);
            short8 v1 = *reinterpret_cast<short8*>(&Vs[dr * 64 + q1]);
            O[ds] = MFMA16(ap0, v0, O[ds]);
            O[ds] = MFMA16(ap1, v1, O[ds]);
        }
        __syncthreads();
    }

    float lr[4];
    #pragma unroll
    for (int r = 0; r < 4; r++) {
        float s = pl[r];
        #pragma unroll
        for (int msk = 1; msk < 16; msk <<= 1) s += __shfl_xor(s, msk);
        lr[r] = s;
    }
    #pragma unroll
    for (int ds = 0; ds < 4; ds++)
        #pragma unroll
        for (int r = 0; r < 4; r++) {
            int q = qbase + quad * 4 + r;
            Po[(size_t)js * 2048 * 1024 + ((size_t)q * 2 + b) * 1024
               + n * 64 + 16 * ds + l16] = f2b(O[ds][r] / lr[r]);
        }
    if (l16 == 0) {
        #pragma unroll
        for (int r = 0; r < 4; r++) {
            int q = qbase + quad * 4 + r;
            size_t idx = (((size_t)js * 2048 + q * 2 + b) * 16 + n) * 2;
            ml[idx] = m_run;
            ml[idx + 1] = lr[r];
        }
    }
}

// ---------------- merge the two j-chunk partials -> AVbf ----------------
__global__ __launch_bounds__(256)
void combine_attn(const bf16* __restrict__ Po, const float* __restrict__ ml,
                  bf16* __restrict__ AVbf) {
    const int m = blockIdx.x;       // row = i*2+b
    const int t = threadIdx.x;
    #pragma unroll
    for (int e = 0; e < 4; e++) {
        int c = e * 256 + t;
        int n = c >> 6;
        size_t i0 = (((size_t)m) * 16 + n) * 2;
        size_t i1 = (((size_t)2048 + m) * 16 + n) * 2;
        float m0 = ml[i0], l0 = ml[i0 + 1];
        float m1 = ml[i1], l1 = ml[i1 + 1];
        float M = fmaxf(m0, m1);
        float w0 = l0 * __expf(m0 - M), w1 = l1 * __expf(m1 - M);
        float inv = 1.f / (w0 + w1);
        float v = (w0 * b2f(Po[(size_t)m * 1024 + c])
                 + w1 * b2f(Po[(size_t)2048 * 1024 + (size_t)m * 1024 + c])) * inv;
        AVbf[(size_t)m * 1024 + c] = f2b(v);
    }
}

// ---------------- out = LN(w + attn_out), f32 ----------------
__global__ __launch_bounds__(256)
void ln_res(const float* __restrict__ ao, const float* __restrict__ w,
            const float* __restrict__ gamma, const float* __restrict__ beta,
            float* __restrict__ out) {
    const int m = blockIdx.x;
    const int t = threadIdx.x;
    __shared__ float red[256];
    float x[4];
    #pragma unroll
    for (int e = 0; e < 4; e++) {
        int c = e * 256 + t;
        x[e] = ao[(size_t)m * DMODEL + c] + w[(size_t)m * DMODEL + c];
    }
    float s = x[0] + x[1] + x[2] + x[3];
    red[t] = s;
    __syncthreads();
    #pragma unroll
    for (int off = 128; off; off >>= 1) {
        if (t < off) red[t] += red[t + off];
        __syncthreads();
    }
    const float mu = red[0] * (1.f / 1024.f);
    __syncthreads();
    float s2 = 0.f;
    #pragma unroll
    for (int e = 0; e < 4; e++) { float dx = x[e] - mu; s2 += dx * dx; }
    red[t] = s2;
    __syncthreads();
    #pragma unroll
    for (int off = 128; off; off >>= 1) {
        if (t < off) red[t] += red[t + off];
        __syncthreads();
    }
    const float rstd = rsqrtf(red[0] * (1.f / 1024.f) + LN_EPS);
    #pragma unroll
    for (int e = 0; e < 4; e++) {
        int c = e * 256 + t;
        out[(size_t)m * DMODEL + c] = (x[e] - mu) * rstd * gamma[c] + beta[c];
    }
}

extern "C" void kernel_launch(void* const* d_in, const int* in_sizes, int n_in,
                              void* d_out, int out_size, void* d_ws, size_t ws_size,
                              hipStream_t stream) {
    const float* w        = (const float*)d_in[0];
    const float* r        = (const float*)d_in[1];
    const float* r_w_bias = (const float*)d_in[2];
    const float* r_r_bias = (const float*)d_in[3];
    const float* mems     = (const float*)d_in[4];
    // d_in[5] attn_mask: deterministic (j <= i+MEMLEN), applied analytically
    const float* W_qkv    = (const float*)d_in[6];
    const float* W_r      = (const float*)d_in[7];
    const float* W_o      = (const float*)d_in[8];
    const float* gamma    = (const float*)d_in[9];
    const float* beta     = (const float*)d_in[10];
    float* out = (float*)d_out;

    // Workspace (~61.5 MB <= 67 MB proven in R2/R4).
    // Po [2,2048,1024] bf16 aliases Abf (dead after QKV GEMM);
    // attn_out f32 aliases the same region (Po dead after combine).
    bf16* Abf    = (bf16*)d_ws;                    // [4096,1024] cat rows m=j*2+b
    bf16* Wqkvt  = Abf   + (size_t)4096 * 1024;    // [3072,1024]
    bf16* Wrt    = Wqkvt + (size_t)3072 * 1024;    // [1024,1024]
    bf16* Wot    = Wrt   + (size_t)1024 * 1024;    // [1024,1024]
    bf16* rbf    = Wot   + (size_t)1024 * 1024;    // [2048,1024]
    bf16* Qw     = rbf   + (size_t)2048 * 1024;    // [2048,1024] rows i*2+b
    bf16* Qr     = Qw    + (size_t)2048 * 1024;
    bf16* Kb     = Qr    + (size_t)2048 * 1024;    // [4096,1024] rows j*2+b
    bf16* Vb     = Kb    + (size_t)4096 * 1024;
    bf16* Vt     = Vb    + (size_t)4096 * 1024;    // [2048,2048] rows d*2+b
    bf16* Rk     = Vt    + (size_t)2048 * 2048;    // [2048,1024]
    bf16* AVbf   = Rk    + (size_t)2048 * 1024;    // [2048,1024]
    float* ml    = (float*)(AVbf + (size_t)2048 * 1024);  // [2,2048,16,2] f32
    bf16* Po     = Abf;                            // [2,2048,1024] partials
    float* attn_out = (float*)Abf;                 // [2048,1024] f32 (alias)

    dim3 b256(256);
    conv_bf16<<<dim3(2048), b256, 0, stream>>>(mems, Abf, 2048 * 256);
    conv_bf16<<<dim3(2048), b256, 0, stream>>>(w, Abf + (size_t)2048 * 1024, 2048 * 256);
    conv_bf16<<<dim3(2048), b256, 0, stream>>>(r, rbf, 2048 * 256);
    conv_wT<<<dim3(48, 16), b256, 0, stream>>>(W_qkv, Wqkvt, 1024, 3072);
    conv_wT<<<dim3(16, 16), b256, 0, stream>>>(W_r, Wrt, 1024, 1024);
    conv_wT<<<dim3(16, 16), b256, 0, stream>>>(W_o, Wot, 1024, 1024);
    gemm_mfma<<<dim3(32, 24), b256, 0, stream>>>(
        Abf, Wqkvt, 4096, 3072, 1024, 0, r_w_bias, r_r_bias,
        Qw, Qr, Kb, Vb, nullptr, nullptr);
    gemm_mfma<<<dim3(16, 8), b256, 0, stream>>>(
        rbf, Wrt, 2048, 1024, 1024, 1, nullptr, nullptr,
        nullptr, nullptr, nullptr, nullptr, Rk, nullptr);
    transpose_v<<<dim3(32, 16, 2), b256, 0, stream>>>(Vb, Vt);
    attn_mfma<<<dim3(1024), b256, 0, stream>>>(Qw, Qr, Kb, Vt, Rk, Po, ml);
    combine_attn<<<dim3(2048), b256, 0, stream>>>(Po, ml, AVbf);
    gemm_mfma<<<dim3(16, 8), b256, 0, stream>>>(
        AVbf, Wot, 2048, 1024, 1024, 2, nullptr, nullptr,
        nullptr, nullptr, nullptr, nullptr, nullptr, attn_out);
    ln_res<<<dim3(QLEN * BSZ), b256, 0, stream>>>(attn_out, w, gamma, beta, out);
}

// Round 11
// 270.143 us; speedup vs baseline: 1.1178x; 1.1178x over previous
//
#include <hip/hip_runtime.h>
#include <hip/hip_bf16.h>

#define NHEAD 16
#define DHEAD 64
#define DMODEL 1024
#define QLEN 1024
#define MEMLEN 1024
#define BSZ 2
#define KLEN 2048
#define LN_EPS 1e-5f

typedef __hip_bfloat16 bf16;
typedef __attribute__((ext_vector_type(8))) short short8;
typedef __attribute__((ext_vector_type(4))) float f32x4;

__device__ __forceinline__ float b2f(bf16 x) { return __bfloat162float(x); }
__device__ __forceinline__ bf16 f2b(float x) { return __float2bfloat16(x); }
__device__ __forceinline__ short f2bs(float f) {
    bf16 h = __float2bfloat16(f);
    return *reinterpret_cast<short*>(&h);
}
__device__ __forceinline__ float s2f(short s) {
    bf16 h = *reinterpret_cast<bf16*>(&s);
    return __bfloat162float(h);
}

#define MFMA16(a, b, c) __builtin_amdgcn_mfma_f32_16x16x32_bf16(a, b, c, 0, 0, 0)

#define AS1 __attribute__((address_space(1)))
#define AS3 __attribute__((address_space(3)))
// async global->LDS, 16B/lane; LDS dest = wave-uniform base + lane*16
__device__ __forceinline__ void gld16(const bf16* g, bf16* l) {
    __builtin_amdgcn_global_load_lds((const AS1 void*)(uintptr_t)g,
                                     (AS3 void*)(uint32_t)(uintptr_t)l, 16, 0, 0);
}

// ---------------- fused f32 -> bf16 flat convert (mems, w, r) ----------------
// grid 6144: [0,2048) mems -> Abf[0:2048); [2048,4096) w -> Abf[2048:4096);
// [4096,6144) r -> rbf. Each block converts 1024 f32 (256 thr x float4).
__global__ __launch_bounds__(256)
void conv_all(const float* __restrict__ mems, const float* __restrict__ w,
              const float* __restrict__ r, bf16* __restrict__ Abf,
              bf16* __restrict__ rbf) {
    const int id = blockIdx.x;
    const float* src;
    bf16* dst;
    int off;
    if (id < 2048)      { src = mems; dst = Abf;                      off = id; }
    else if (id < 4096) { src = w;    dst = Abf + (size_t)2048 * 1024; off = id - 2048; }
    else                { src = r;    dst = rbf;                      off = id - 4096; }
    int i = off * 256 + threadIdx.x;
    const float4 v = reinterpret_cast<const float4*>(src)[i];
    bf16 o[4] = {f2b(v.x), f2b(v.y), f2b(v.z), f2b(v.w)};
    reinterpret_cast<ulong1*>(dst)[i] = *reinterpret_cast<ulong1*>(o);
}

// ---------------- fused f32 [K][N] -> bf16 [N][K] transpose-convert ----------------
// grid 1280: [0,768) W_qkv (N=3072), [768,1024) W_r, [1024,1280) W_o.
__global__ __launch_bounds__(256)
void conv_wT_all(const float* __restrict__ Wqkv, const float* __restrict__ Wr,
                 const float* __restrict__ Wo, bf16* __restrict__ Wqkvt,
                 bf16* __restrict__ Wrt, bf16* __restrict__ Wot) {
    __shared__ bf16 T[64][65];
    const int id = blockIdx.x;
    const float* in;
    bf16* out;
    int N, tn, tile;
    if (id < 768)       { in = Wqkv; out = Wqkvt; N = 3072; tn = 48; tile = id; }
    else if (id < 1024) { in = Wr;   out = Wrt;   N = 1024; tn = 16; tile = id - 768; }
    else                { in = Wo;   out = Wot;   N = 1024; tn = 16; tile = id - 1024; }
    const int K = 1024;
    const int n0 = (tile % tn) * 64, k0 = (tile / tn) * 64;
    const int t = threadIdx.x;
    #pragma unroll
    for (int e = 0; e < 16; e++) {
        int flat = e * 256 + t;
        int kl = flat >> 6, nl = flat & 63;
        T[kl][nl] = f2b(in[(size_t)(k0 + kl) * N + n0 + nl]);
    }
    __syncthreads();
    #pragma unroll
    for (int e = 0; e < 16; e++) {
        int flat = e * 256 + t;
        int nl = flat >> 6, kl = flat & 63;
        out[(size_t)(n0 + nl) * K + k0 + kl] = T[kl][nl];
    }
}

// ---------------- MFMA GEMM (m97 staging): C = A[M,K] @ Bt[N,K]^T ----------------
// 128x128 tile, BK=32, global_load_lds width-16 into unpadded [128][32] LDS.
// mode 0 (QKV): blocks with bm<2048 && bn<1024 (never-used mem-row Q tiles)
// are RECYCLED to compute Rk = rbf @ Wrt (same tile coords, K=1024).
// mode 2: f32 store to Cf.
__global__ __launch_bounds__(256)
void gemm_mfma(const bf16* __restrict__ A, const bf16* __restrict__ Bt,
               const bf16* __restrict__ A2, const bf16* __restrict__ B2,
               int M, int N, int K, int mode,
               const float* __restrict__ rwb, const float* __restrict__ rrb,
               bf16* __restrict__ Qw, bf16* __restrict__ Qr,
               bf16* __restrict__ Kb, bf16* __restrict__ Vb,
               bf16* __restrict__ Cb, float* __restrict__ Cf) {
    const int bm = blockIdx.x * 128, bn = blockIdx.y * 128;
    int sub = 0;
    const bf16* Ap = A;
    const bf16* Bp = Bt;
    if (mode == 0 && bm < 2048 && bn < 1024) { sub = 1; Ap = A2; Bp = B2; }
    __shared__ bf16 As[128 * 32];
    __shared__ bf16 Bs[128 * 32];
    const int t = threadIdx.x;
    const int w = t >> 6, lane = t & 63, quad = lane >> 4, l16 = lane & 15;
    const int wm = (w >> 1) * 64, wn = (w & 1) * 64;
    const int lrow = lane >> 2, lcol = (lane & 3) * 8;

    f32x4 acc[4][4];
    #pragma unroll
    for (int mt = 0; mt < 4; mt++)
        #pragma unroll
        for (int nt = 0; nt < 4; nt++) acc[mt][nt] = (f32x4){0.f, 0.f, 0.f, 0.f};

    for (int k0 = 0; k0 < K; k0 += 32) {
        #pragma unroll
        for (int e = 0; e < 2; e++) {
            int ch = w + 4 * e;                       // 0..7, wave-uniform
            int row = ch * 16 + lrow;
            gld16(Ap + (size_t)(bm + row) * K + k0 + lcol, As + ch * 512);
            gld16(Bp + (size_t)(bn + row) * K + k0 + lcol, Bs + ch * 512);
        }
        __syncthreads();
        short8 af[4], bfr[4];
        #pragma unroll
        for (int mt = 0; mt < 4; mt++)
            af[mt] = *reinterpret_cast<short8*>(&As[(wm + 16 * mt + l16) * 32 + quad * 8]);
        #pragma unroll
        for (int nt = 0; nt < 4; nt++)
            bfr[nt] = *reinterpret_cast<short8*>(&Bs[(wn + 16 * nt + l16) * 32 + quad * 8]);
        #pragma unroll
        for (int mt = 0; mt < 4; mt++)
            #pragma unroll
            for (int nt = 0; nt < 4; nt++)
                acc[mt][nt] = MFMA16(af[mt], bfr[nt], acc[mt][nt]);
        __syncthreads();
    }

    #pragma unroll
    for (int mt = 0; mt < 4; mt++)
        #pragma unroll
        for (int nt = 0; nt < 4; nt++)
            #pragma unroll
            for (int r = 0; r < 4; r++) {
                int m = bm + wm + 16 * mt + quad * 4 + r;
                int c = bn + wn + 16 * nt + l16;
                float v = acc[mt][nt][r];
                if (sub) {
                    Cb[(size_t)m * 1024 + c] = f2b(v);   // Rk tile
                } else if (mode == 0) {
                    int seg = c >> 10, cc = c & 1023;
                    if (seg == 0) {
                        if (m >= 2048) {
                            size_t o = (size_t)(m - 2048) * 1024 + cc;
                            Qw[o] = f2b(v + rwb[cc]);
                            Qr[o] = f2b(v + rrb[cc]);
                        }
                    } else if (seg == 1) Kb[(size_t)m * 1024 + cc] = f2b(v);
                    else                 Vb[(size_t)m * 1024 + cc] = f2b(v);
                } else {
                    Cf[(size_t)m * N + c] = v;
                }
            }
}

// ---------------- V transpose: Vb[j*2+b][d] -> Vt[(d*2+b)][j] ----------------
__global__ __launch_bounds__(256)
void transpose_v(const bf16* __restrict__ Vb, bf16* __restrict__ Vt) {
    __shared__ bf16 T[64][65];
    const int J0 = blockIdx.x * 64, D0 = blockIdx.y * 64, b = blockIdx.z;
    const int t = threadIdx.x;
    #pragma unroll
    for (int e = 0; e < 16; e++) {
        int flat = e * 256 + t;
        int jl = flat >> 6, dl = flat & 63;
        T[jl][dl] = Vb[(size_t)((J0 + jl) * 2 + b) * 1024 + D0 + dl];
    }
    __syncthreads();
    #pragma unroll
    for (int e = 0; e < 16; e++) {
        int flat = e * 256 + t;
        int dl = flat >> 6, jl = flat & 63;
        Vt[(size_t)((D0 + dl) * 2 + b) * 2048 + J0 + jl] = T[jl][dl];
    }
}

// ---------------- MFMA flash attention, LDS-staged, split-J partials ----------------
// (R10-verified, unchanged.) 256 thr = 4 waves, 64 q-rows, half J range.
__global__ __launch_bounds__(256, 3)
void attn_mfma(const bf16* __restrict__ Qw, const bf16* __restrict__ Qr,
               const bf16* __restrict__ Kb, const bf16* __restrict__ Vt,
               const bf16* __restrict__ Rk, bf16* __restrict__ Po,
               float* __restrict__ ml) {
    const int id = blockIdx.x;
    const int xcd = id & 7, local = id >> 3;
    const int pair = xcd * 4 + (local & 3);
    const int i0 = (local >> 2) & 15;
    const int js = local >> 6;
    const int b = pair & 1, n = pair >> 1;
    const int I0 = i0 * 64;

    const int tid = threadIdx.x;
    const int w = tid >> 6, lane = tid & 63;
    const int quad = lane >> 4, l16 = lane & 15;
    const int qbase = I0 + 16 * w;
    const int ln8 = lane >> 3;
    const int cs = (lane & 7) ^ (ln8 & 7);
    const int q0 = (quad ^ (l16 & 7)) * 8;
    const int q1 = q0 ^ 32;

    __shared__ bf16 Ks[64 * 64];
    __shared__ bf16 Vs[64 * 64];
    __shared__ bf16 Rs[128 * 64];
    __shared__ short WlB_s[4][16 * 80];
    __shared__ short Pb_s[4][16 * 72];
    short* WlB = WlB_s[w];
    short* Pb = Pb_s[w];

    short8 aqw[2], aqr[2];
    {
        const bf16* qp = Qw + ((size_t)(qbase + l16) * 2 + b) * 1024 + n * 64 + quad * 8;
        aqw[0] = *reinterpret_cast<const short8*>(qp);
        aqw[1] = *reinterpret_cast<const short8*>(qp + 32);
        const bf16* qp2 = Qr + ((size_t)(qbase + l16) * 2 + b) * 1024 + n * 64 + quad * 8;
        aqr[0] = *reinterpret_cast<const short8*>(qp2);
        aqr[1] = *reinterpret_cast<const short8*>(qp2 + 32);
    }

    f32x4 O[4];
    #pragma unroll
    for (int d = 0; d < 4; d++) O[d] = (f32x4){0.f, 0.f, 0.f, 0.f};
    float m_run = -1e30f;
    float pl[4] = {0.f, 0.f, 0.f, 0.f};

    const int T = i0 + 17;
    const int t0 = js ? (T >> 1) : 0;
    const int t1 = js ? T : (T >> 1);
    const int koff = b * 1024 + n * 64 + cs * 8;
    const size_t voff = (size_t)n * 262144 + b * 2048 + cs * 8;
    const int rcol = n * 64 + cs * 8;
    const int rbl = 48 - 16 * w;

    for (int tt = t0; tt < t1; tt++) {
        const int J0 = tt * 64;
        const int RU0 = J0 - I0 + 960;

        #pragma unroll
        for (int e = 0; e < 2; e++) {
            int ch = w + 4 * e;
            int krow = J0 + ch * 8 + ln8;
            gld16(Kb + (size_t)krow * 2048 + koff, Ks + ch * 512);
            int dl = ch * 8 + ln8;
            gld16(Vt + (size_t)dl * 4096 + voff + J0, Vs + ch * 512);
        }
        #pragma unroll
        for (int e = 0; e < 4; e++) {
            int ch = w + 4 * e;
            int rrow = RU0 + ch * 8 + ln8;
            rrow = min(rrow, 2047);
            gld16(Rk + (size_t)rrow * 1024 + rcol, Rs + ch * 512);
        }
        __syncthreads();

        #pragma unroll
        for (int s = 0; s < 5; s++) {
            int rl = rbl + 16 * s + l16;
            short8 b0 = *reinterpret_cast<short8*>(&Rs[rl * 64 + q0]);
            short8 b1 = *reinterpret_cast<short8*>(&Rs[rl * 64 + q1]);
            f32x4 acc = (f32x4){0.f, 0.f, 0.f, 0.f};
            acc = MFMA16(aqr[0], b0, acc);
            acc = MFMA16(aqr[1], b1, acc);
            #pragma unroll
            for (int r = 0; r < 4; r++)
                WlB[(quad * 4 + r) * 80 + 16 * s + l16] = f2bs(acc[r]);
        }

        float sv[4][4];
        #pragma unroll
        for (int n16 = 0; n16 < 4; n16++) {
            int kr = 16 * n16 + l16;
            short8 k0 = *reinterpret_cast<short8*>(&Ks[kr * 64 + q0]);
            short8 k1 = *reinterpret_cast<short8*>(&Ks[kr * 64 + q1]);
            f32x4 acc = (f32x4){0.f, 0.f, 0.f, 0.f};
            acc = MFMA16(aqw[0], k0, acc);
            acc = MFMA16(aqw[1], k1, acc);
            #pragma unroll
            for (int r = 0; r < 4; r++) {
                int row = quad * 4 + r, col = 16 * n16 + l16;
                float s = (acc[r] + s2f(WlB[row * 80 + col - row + 15])) * 0.125f;
                if (J0 + col > qbase + row + MEMLEN) s = -1e30f;
                sv[n16][r] = s;
            }
        }

        float mx = sv[0][0];
        #pragma unroll
        for (int n16 = 0; n16 < 4; n16++)
            #pragma unroll
            for (int r = 0; r < 4; r++) mx = fmaxf(mx, sv[n16][r]);
        #pragma unroll
        for (int msk = 1; msk < 16; msk <<= 1) mx = fmaxf(mx, __shfl_xor(mx, msk));
        const float mn = fmaxf(m_run, mx);
        const float alpha = __expf(m_run - mn);
        m_run = mn;
        #pragma unroll
        for (int n16 = 0; n16 < 4; n16++)
            #pragma unroll
            for (int r = 0; r < 4; r++) sv[n16][r] = __expf(sv[n16][r] - mn);
        #pragma unroll
        for (int r = 0; r < 4; r++)
            pl[r] = pl[r] * alpha + (sv[0][r] + sv[1][r] + sv[2][r] + sv[3][r]);
        #pragma unroll
        for (int d = 0; d < 4; d++)
            #pragma unroll
            for (int r = 0; r < 4; r++) O[d][r] *= alpha;

        #pragma unroll
        for (int n16 = 0; n16 < 4; n16++)
            #pragma unroll
            for (int r = 0; r < 4; r++)
                Pb[(quad * 4 + r) * 72 + 16 * n16 + l16] = f2bs(sv[n16][r]);
        short8 ap0 = *reinterpret_cast<short8*>(&Pb[l16 * 72 + quad * 8]);
        short8 ap1 = *reinterpret_cast<short8*>(&Pb[l16 * 72 + 32 + quad * 8]);

        #pragma unroll
        for (int ds = 0; ds < 4; ds++) {
            int dr = 16 * ds + l16;
            short8 v0 = *reinterpret_cast<short8*>(&Vs[dr * 64 + q0]);
            short8 v1 = *reinterpret_cast<short8*>(&Vs[dr * 64 + q1]);
            O[ds] = MFMA16(ap0, v0, O[ds]);
            O[ds] = MFMA16(ap1, v1, O[ds]);
        }
        __syncthreads();
    }

    float lr[4];
    #pragma unroll
    for (int r = 0; r < 4; r++) {
        float s = pl[r];
        #pragma unroll
        for (int msk = 1; msk < 16; msk <<= 1) s += __shfl_xor(s, msk);
        lr[r] = s;
    }
    #pragma unroll
    for (int ds = 0; ds < 4; ds++)
        #pragma unroll
        for (int r = 0; r < 4; r++) {
            int q = qbase + quad * 4 + r;
            Po[(size_t)js * 2048 * 1024 + ((size_t)q * 2 + b) * 1024
               + n * 64 + 16 * ds + l16] = f2b(O[ds][r] / lr[r]);
        }
    if (l16 == 0) {
        #pragma unroll
        for (int r = 0; r < 4; r++) {
            int q = qbase + quad * 4 + r;
            size_t idx = (((size_t)js * 2048 + q * 2 + b) * 16 + n) * 2;
            ml[idx] = m_run;
            ml[idx + 1] = lr[r];
        }
    }
}

// ---------------- merge the two j-chunk partials -> AVbf ----------------
__global__ __launch_bounds__(256)
void combine_attn(const bf16* __restrict__ Po, const float* __restrict__ ml,
                  bf16* __restrict__ AVbf) {
    const int m = blockIdx.x;
    const int t = threadIdx.x;
    #pragma unroll
    for (int e = 0; e < 4; e++) {
        int c = e * 256 + t;
        int n = c >> 6;
        size_t i0 = (((size_t)m) * 16 + n) * 2;
        size_t i1 = (((size_t)2048 + m) * 16 + n) * 2;
        float m0 = ml[i0], l0 = ml[i0 + 1];
        float m1 = ml[i1], l1 = ml[i1 + 1];
        float M = fmaxf(m0, m1);
        float w0 = l0 * __expf(m0 - M), w1 = l1 * __expf(m1 - M);
        float inv = 1.f / (w0 + w1);
        float v = (w0 * b2f(Po[(size_t)m * 1024 + c])
                 + w1 * b2f(Po[(size_t)2048 * 1024 + (size_t)m * 1024 + c])) * inv;
        AVbf[(size_t)m * 1024 + c] = f2b(v);
    }
}

// ---------------- out = LN(w + attn_out), f32 ----------------
__global__ __launch_bounds__(256)
void ln_res(const float* __restrict__ ao, const float* __restrict__ w,
            const float* __restrict__ gamma, const float* __restrict__ beta,
            float* __restrict__ out) {
    const int m = blockIdx.x;
    const int t = threadIdx.x;
    __shared__ float red[256];
    float x[4];
    #pragma unroll
    for (int e = 0; e < 4; e++) {
        int c = e * 256 + t;
        x[e] = ao[(size_t)m * DMODEL + c] + w[(size_t)m * DMODEL + c];
    }
    float s = x[0] + x[1] + x[2] + x[3];
    red[t] = s;
    __syncthreads();
    #pragma unroll
    for (int off = 128; off; off >>= 1) {
        if (t < off) red[t] += red[t + off];
        __syncthreads();
    }
    const float mu = red[0] * (1.f / 1024.f);
    __syncthreads();
    float s2 = 0.f;
    #pragma unroll
    for (int e = 0; e < 4; e++) { float dx = x[e] - mu; s2 += dx * dx; }
    red[t] = s2;
    __syncthreads();
    #pragma unroll
    for (int off = 128; off; off >>= 1) {
        if (t < off) red[t] += red[t + off];
        __syncthreads();
    }
    const float rstd = rsqrtf(red[0] * (1.f / 1024.f) + LN_EPS);
    #pragma unroll
    for (int e = 0; e < 4; e++) {
        int c = e * 256 + t;
        out[(size_t)m * DMODEL + c] = (x[e] - mu) * rstd * gamma[c] + beta[c];
    }
}

extern "C" void kernel_launch(void* const* d_in, const int* in_sizes, int n_in,
                              void* d_out, int out_size, void* d_ws, size_t ws_size,
                              hipStream_t stream) {
    const float* w        = (const float*)d_in[0];
    const float* r        = (const float*)d_in[1];
    const float* r_w_bias = (const float*)d_in[2];
    const float* r_r_bias = (const float*)d_in[3];
    const float* mems     = (const float*)d_in[4];
    // d_in[5] attn_mask: deterministic (j <= i+MEMLEN), applied analytically
    const float* W_qkv    = (const float*)d_in[6];
    const float* W_r      = (const float*)d_in[7];
    const float* W_o      = (const float*)d_in[8];
    const float* gamma    = (const float*)d_in[9];
    const float* beta     = (const float*)d_in[10];
    float* out = (float*)d_out;

    // Workspace (~61.5 MB). Po [2,2048,1024] bf16 aliases Abf (dead after
    // QKV GEMM); attn_out f32 aliases the same region (Po dead after combine).
    bf16* Abf    = (bf16*)d_ws;                    // [4096,1024] cat rows m=j*2+b
    bf16* Wqkvt  = Abf   + (size_t)4096 * 1024;    // [3072,1024]
    bf16* Wrt    = Wqkvt + (size_t)3072 * 1024;    // [1024,1024]
    bf16* Wot    = Wrt   + (size_t)1024 * 1024;    // [1024,1024]
    bf16* rbf    = Wot   + (size_t)1024 * 1024;    // [2048,1024]
    bf16* Qw     = rbf   + (size_t)2048 * 1024;    // [2048,1024] rows i*2+b
    bf16* Qr     = Qw    + (size_t)2048 * 1024;
    bf16* Kb     = Qr    + (size_t)2048 * 1024;    // [4096,1024] rows j*2+b
    bf16* Vb     = Kb    + (size_t)4096 * 1024;
    bf16* Vt     = Vb    + (size_t)4096 * 1024;    // [2048,2048] rows d*2+b
    bf16* Rk     = Vt    + (size_t)2048 * 2048;    // [2048,1024]
    bf16* AVbf   = Rk    + (size_t)2048 * 1024;    // [2048,1024]
    float* ml    = (float*)(AVbf + (size_t)2048 * 1024);  // [2,2048,16,2] f32
    bf16* Po     = Abf;                            // [2,2048,1024] partials
    float* attn_out = (float*)Abf;                 // [2048,1024] f32 (alias)

    dim3 b256(256);
    conv_all<<<dim3(6144), b256, 0, stream>>>(mems, w, r, Abf, rbf);
    conv_wT_all<<<dim3(1280), b256, 0, stream>>>(W_qkv, W_r, W_o, Wqkvt, Wrt, Wot);
    // QKV GEMM + recycled-tile Rk GEMM in one launch
    gemm_mfma<<<dim3(32, 24), b256, 0, stream>>>(
        Abf, Wqkvt, rbf, Wrt, 4096, 3072, 1024, 0, r_w_bias, r_r_bias,
        Qw, Qr, Kb, Vb, Rk, nullptr);
    transpose_v<<<dim3(32, 16, 2), b256, 0, stream>>>(Vb, Vt);
    attn_mfma<<<dim3(1024), b256, 0, stream>>>(Qw, Qr, Kb, Vt, Rk, Po, ml);
    combine_attn<<<dim3(2048), b256, 0, stream>>>(Po, ml, AVbf);
    gemm_mfma<<<dim3(16, 8), b256, 0, stream>>>(
        AVbf, Wot, nullptr, nullptr, 2048, 1024, 1024, 2, nullptr, nullptr,
        nullptr, nullptr, nullptr, nullptr, nullptr, attn_out);
    ln_res<<<dim3(QLEN * BSZ), b256, 0, stream>>>(attn_out, w, gamma, beta, out);
}

// Round 12
// 263.374 us; speedup vs baseline: 1.1466x; 1.0257x over previous
//
#include <hip/hip_runtime.h>
#include <hip/hip_bf16.h>

#define NHEAD 16
#define DHEAD 64
#define DMODEL 1024
#define QLEN 1024
#define MEMLEN 1024
#define BSZ 2
#define KLEN 2048
#define LN_EPS 1e-5f

typedef __hip_bfloat16 bf16;
typedef __attribute__((ext_vector_type(8))) short short8;
typedef __attribute__((ext_vector_type(4))) float f32x4;

__device__ __forceinline__ float b2f(bf16 x) { return __bfloat162float(x); }
__device__ __forceinline__ bf16 f2b(float x) { return __float2bfloat16(x); }
__device__ __forceinline__ short f2bs(float f) {
    bf16 h = __float2bfloat16(f);
    return *reinterpret_cast<short*>(&h);
}
__device__ __forceinline__ float s2f(short s) {
    bf16 h = *reinterpret_cast<bf16*>(&s);
    return __bfloat162float(h);
}

#define MFMA16(a, b, c) __builtin_amdgcn_mfma_f32_16x16x32_bf16(a, b, c, 0, 0, 0)

#define AS1 __attribute__((address_space(1)))
#define AS3 __attribute__((address_space(3)))
// async global->LDS, 16B/lane; LDS dest = wave-uniform base + lane*16
__device__ __forceinline__ void gld16(const bf16* g, bf16* l) {
    __builtin_amdgcn_global_load_lds((const AS1 void*)(uintptr_t)g,
                                     (AS3 void*)(uint32_t)(uintptr_t)l, 16, 0, 0);
}

// ---------------- fused prep: flat converts + weight transposes ----------------
// grid 7424:
//   [0,2048)    mems -> Abf[0:2048)        (1024 f32 per block, float4)
//   [2048,4096) w    -> Abf[2048:4096)
//   [4096,6144) r    -> rbf
//   [6144,6912) W_qkv -> Wqkvt (64x64 transpose tiles, N=3072)
//   [6912,7168) W_r   -> Wrt
//   [7168,7424) W_o   -> Wot
__global__ __launch_bounds__(256)
void prep(const float* __restrict__ mems, const float* __restrict__ w,
          const float* __restrict__ r, const float* __restrict__ Wqkv,
          const float* __restrict__ Wr, const float* __restrict__ Wo,
          bf16* __restrict__ Abf, bf16* __restrict__ rbf,
          bf16* __restrict__ Wqkvt, bf16* __restrict__ Wrt,
          bf16* __restrict__ Wot) {
    __shared__ bf16 T[64][65];
    const int id = blockIdx.x;
    const int t = threadIdx.x;
    if (id < 6144) {
        const float* src;
        bf16* dst;
        int off;
        if (id < 2048)      { src = mems; dst = Abf;                       off = id; }
        else if (id < 4096) { src = w;    dst = Abf + (size_t)2048 * 1024; off = id - 2048; }
        else                { src = r;    dst = rbf;                       off = id - 4096; }
        int i = off * 256 + t;
        const float4 v = reinterpret_cast<const float4*>(src)[i];
        bf16 o[4] = {f2b(v.x), f2b(v.y), f2b(v.z), f2b(v.w)};
        reinterpret_cast<ulong1*>(dst)[i] = *reinterpret_cast<ulong1*>(o);
        return;
    }
    int tid2 = id - 6144;
    const float* in;
    bf16* out;
    int N, tn, tile;
    if (tid2 < 768)       { in = Wqkv; out = Wqkvt; N = 3072; tn = 48; tile = tid2; }
    else if (tid2 < 1024) { in = Wr;   out = Wrt;   N = 1024; tn = 16; tile = tid2 - 768; }
    else                  { in = Wo;   out = Wot;   N = 1024; tn = 16; tile = tid2 - 1024; }
    const int K = 1024;
    const int n0 = (tile % tn) * 64, k0 = (tile / tn) * 64;
    #pragma unroll
    for (int e = 0; e < 16; e++) {
        int flat = e * 256 + t;
        int kl = flat >> 6, nl = flat & 63;
        T[kl][nl] = f2b(in[(size_t)(k0 + kl) * N + n0 + nl]);
    }
    __syncthreads();
    #pragma unroll
    for (int e = 0; e < 16; e++) {
        int flat = e * 256 + t;
        int nl = flat >> 6, kl = flat & 63;
        out[(size_t)(n0 + nl) * K + k0 + kl] = T[kl][nl];
    }
}

// ---------------- MFMA GEMM (m97 staging): C = A[M,K] @ Bt[N,K]^T ----------------
// 128x128 tile, BK=32, global_load_lds width-16 into unpadded [128][32] LDS.
// mode 0 (QKV): blocks with bm<2048 && bn<1024 (never-used mem-row Q tiles) are
// RECYCLED to compute Rk = rbf @ Wrt. V segment writes Vt DIRECTLY (transposed):
// Vt[(c*2+b)][m>>1] (L2 write-combines the 2B scatters). mode 2: f32 store.
__global__ __launch_bounds__(256)
void gemm_mfma(const bf16* __restrict__ A, const bf16* __restrict__ Bt,
               const bf16* __restrict__ A2, const bf16* __restrict__ B2,
               int M, int N, int K, int mode,
               const float* __restrict__ rwb, const float* __restrict__ rrb,
               bf16* __restrict__ Qw, bf16* __restrict__ Qr,
               bf16* __restrict__ Kb, bf16* __restrict__ Vt,
               bf16* __restrict__ Cb, float* __restrict__ Cf) {
    const int bm = blockIdx.x * 128, bn = blockIdx.y * 128;
    int sub = 0;
    const bf16* Ap = A;
    const bf16* Bp = Bt;
    if (mode == 0 && bm < 2048 && bn < 1024) { sub = 1; Ap = A2; Bp = B2; }
    __shared__ bf16 As[128 * 32];
    __shared__ bf16 Bs[128 * 32];
    const int t = threadIdx.x;
    const int w = t >> 6, lane = t & 63, quad = lane >> 4, l16 = lane & 15;
    const int wm = (w >> 1) * 64, wn = (w & 1) * 64;
    const int lrow = lane >> 2, lcol = (lane & 3) * 8;

    f32x4 acc[4][4];
    #pragma unroll
    for (int mt = 0; mt < 4; mt++)
        #pragma unroll
        for (int nt = 0; nt < 4; nt++) acc[mt][nt] = (f32x4){0.f, 0.f, 0.f, 0.f};

    for (int k0 = 0; k0 < K; k0 += 32) {
        #pragma unroll
        for (int e = 0; e < 2; e++) {
            int ch = w + 4 * e;                       // 0..7, wave-uniform
            int row = ch * 16 + lrow;
            gld16(Ap + (size_t)(bm + row) * K + k0 + lcol, As + ch * 512);
            gld16(Bp + (size_t)(bn + row) * K + k0 + lcol, Bs + ch * 512);
        }
        __syncthreads();
        short8 af[4], bfr[4];
        #pragma unroll
        for (int mt = 0; mt < 4; mt++)
            af[mt] = *reinterpret_cast<short8*>(&As[(wm + 16 * mt + l16) * 32 + quad * 8]);
        #pragma unroll
        for (int nt = 0; nt < 4; nt++)
            bfr[nt] = *reinterpret_cast<short8*>(&Bs[(wn + 16 * nt + l16) * 32 + quad * 8]);
        #pragma unroll
        for (int mt = 0; mt < 4; mt++)
            #pragma unroll
            for (int nt = 0; nt < 4; nt++)
                acc[mt][nt] = MFMA16(af[mt], bfr[nt], acc[mt][nt]);
        __syncthreads();
    }

    #pragma unroll
    for (int mt = 0; mt < 4; mt++)
        #pragma unroll
        for (int nt = 0; nt < 4; nt++)
            #pragma unroll
            for (int r = 0; r < 4; r++) {
                int m = bm + wm + 16 * mt + quad * 4 + r;
                int c = bn + wn + 16 * nt + l16;
                float v = acc[mt][nt][r];
                if (sub) {
                    Cb[(size_t)m * 1024 + c] = f2b(v);   // Rk tile
                } else if (mode == 0) {
                    int seg = c >> 10, cc = c & 1023;
                    if (seg == 0) {
                        if (m >= 2048) {
                            size_t o = (size_t)(m - 2048) * 1024 + cc;
                            Qw[o] = f2b(v + rwb[cc]);
                            Qr[o] = f2b(v + rrb[cc]);
                        }
                    } else if (seg == 1) {
                        Kb[(size_t)m * 1024 + cc] = f2b(v);
                    } else {
                        // V: write transposed Vt[(cc*2 + b)][j], j=m>>1, b=m&1
                        Vt[((size_t)cc * 2 + (m & 1)) * 2048 + (m >> 1)] = f2b(v);
                    }
                } else {
                    Cf[(size_t)m * N + c] = v;
                }
            }
}

// ---------------- MFMA flash attention, LDS-staged, full-J ----------------
// 256 thr = 4 waves; block = 64 q-rows, full J range. LDS 51KB -> 3 blocks/CU.
// Grid 512 = 8 xcd * (4 pairs * 16 i0), pair pinned per XCD for L2 reuse.
__global__ __launch_bounds__(256, 3)
void attn_mfma(const bf16* __restrict__ Qw, const bf16* __restrict__ Qr,
               const bf16* __restrict__ Kb, const bf16* __restrict__ Vt,
               const bf16* __restrict__ Rk, bf16* __restrict__ AVbf) {
    const int id = blockIdx.x;
    const int xcd = id & 7, local = id >> 3;          // local 0..63
    const int pair = xcd * 4 + (local & 3);           // 0..31
    const int i0 = local >> 2;                        // 0..15
    const int b = pair & 1, n = pair >> 1;
    const int I0 = i0 * 64;

    const int tid = threadIdx.x;
    const int w = tid >> 6, lane = tid & 63;
    const int quad = lane >> 4, l16 = lane & 15;
    const int qbase = I0 + 16 * w;
    const int ln8 = lane >> 3;
    const int cs = (lane & 7) ^ (ln8 & 7);            // swizzled source chunk
    const int q0 = (quad ^ (l16 & 7)) * 8;            // frag chunk (k 0..31)
    const int q1 = q0 ^ 32;

    __shared__ bf16 Ks[64 * 64];
    __shared__ bf16 Vs[64 * 64];
    __shared__ bf16 Rs[128 * 64];
    __shared__ short WlB_s[4][16 * 80];   // rel-shift window, bf16
    __shared__ short Pb_s[4][16 * 72];
    short* WlB = WlB_s[w];
    short* Pb = Pb_s[w];

    short8 aqw[2], aqr[2];
    {
        const bf16* qp = Qw + ((size_t)(qbase + l16) * 2 + b) * 1024 + n * 64 + quad * 8;
        aqw[0] = *reinterpret_cast<const short8*>(qp);
        aqw[1] = *reinterpret_cast<const short8*>(qp + 32);
        const bf16* qp2 = Qr + ((size_t)(qbase + l16) * 2 + b) * 1024 + n * 64 + quad * 8;
        aqr[0] = *reinterpret_cast<const short8*>(qp2);
        aqr[1] = *reinterpret_cast<const short8*>(qp2 + 32);
    }

    f32x4 O[4];
    #pragma unroll
    for (int d = 0; d < 4; d++) O[d] = (f32x4){0.f, 0.f, 0.f, 0.f};
    float m_run = -1e30f;
    float pl[4] = {0.f, 0.f, 0.f, 0.f};

    const int T = i0 + 17;
    const int koff = b * 1024 + n * 64 + cs * 8;
    const size_t voff = (size_t)n * 262144 + b * 2048 + cs * 8;
    const int rcol = n * 64 + cs * 8;
    const int rbl = 48 - 16 * w;

    for (int tt = 0; tt < T; tt++) {
        const int J0 = tt * 64;
        const int RU0 = J0 - I0 + 960;

        #pragma unroll
        for (int e = 0; e < 2; e++) {
            int ch = w + 4 * e;
            int krow = J0 + ch * 8 + ln8;
            gld16(Kb + (size_t)krow * 2048 + koff, Ks + ch * 512);
            int dl = ch * 8 + ln8;
            gld16(Vt + (size_t)dl * 4096 + voff + J0, Vs + ch * 512);
        }
        #pragma unroll
        for (int e = 0; e < 4; e++) {
            int ch = w + 4 * e;
            int rrow = RU0 + ch * 8 + ln8;
            rrow = min(rrow, 2047);                   // OOB rows hit only masked pairs
            gld16(Rk + (size_t)rrow * 1024 + rcol, Rs + ch * 512);
        }
        __syncthreads();

        // ---- BD window GEMM from Rs ----
        #pragma unroll
        for (int s = 0; s < 5; s++) {
            int rl = rbl + 16 * s + l16;
            short8 b0 = *reinterpret_cast<short8*>(&Rs[rl * 64 + q0]);
            short8 b1 = *reinterpret_cast<short8*>(&Rs[rl * 64 + q1]);
            f32x4 acc = (f32x4){0.f, 0.f, 0.f, 0.f};
            acc = MFMA16(aqr[0], b0, acc);
            acc = MFMA16(aqr[1], b1, acc);
            #pragma unroll
            for (int r = 0; r < 4; r++)
                WlB[(quad * 4 + r) * 80 + 16 * s + l16] = f2bs(acc[r]);
        }

        // ---- AC GEMM from Ks + score assembly ----
        float sv[4][4];
        #pragma unroll
        for (int n16 = 0; n16 < 4; n16++) {
            int kr = 16 * n16 + l16;
            short8 k0 = *reinterpret_cast<short8*>(&Ks[kr * 64 + q0]);
            short8 k1 = *reinterpret_cast<short8*>(&Ks[kr * 64 + q1]);
            f32x4 acc = (f32x4){0.f, 0.f, 0.f, 0.f};
            acc = MFMA16(aqw[0], k0, acc);
            acc = MFMA16(aqw[1], k1, acc);
            #pragma unroll
            for (int r = 0; r < 4; r++) {
                int row = quad * 4 + r, col = 16 * n16 + l16;
                float s = (acc[r] + s2f(WlB[row * 80 + col - row + 15])) * 0.125f;
                if (J0 + col > qbase + row + MEMLEN) s = -1e30f;
                sv[n16][r] = s;
            }
        }

        // ---- online softmax (shared per-quad max) ----
        float mx = sv[0][0];
        #pragma unroll
        for (int n16 = 0; n16 < 4; n16++)
            #pragma unroll
            for (int r = 0; r < 4; r++) mx = fmaxf(mx, sv[n16][r]);
        #pragma unroll
        for (int msk = 1; msk < 16; msk <<= 1) mx = fmaxf(mx, __shfl_xor(mx, msk));
        const float mn = fmaxf(m_run, mx);
        const float alpha = __expf(m_run - mn);
        m_run = mn;
        #pragma unroll
        for (int n16 = 0; n16 < 4; n16++)
            #pragma unroll
            for (int r = 0; r < 4; r++) sv[n16][r] = __expf(sv[n16][r] - mn);
        #pragma unroll
        for (int r = 0; r < 4; r++)
            pl[r] = pl[r] * alpha + (sv[0][r] + sv[1][r] + sv[2][r] + sv[3][r]);
        #pragma unroll
        for (int d = 0; d < 4; d++)
            #pragma unroll
            for (int r = 0; r < 4; r++) O[d][r] *= alpha;

        // ---- P -> LDS bf16 (C-layout), read back as A-frags ----
        #pragma unroll
        for (int n16 = 0; n16 < 4; n16++)
            #pragma unroll
            for (int r = 0; r < 4; r++)
                Pb[(quad * 4 + r) * 72 + 16 * n16 + l16] = f2bs(sv[n16][r]);
        short8 ap0 = *reinterpret_cast<short8*>(&Pb[l16 * 72 + quad * 8]);
        short8 ap1 = *reinterpret_cast<short8*>(&Pb[l16 * 72 + 32 + quad * 8]);

        // ---- PV from Vs ----
        #pragma unroll
        for (int ds = 0; ds < 4; ds++) {
            int dr = 16 * ds + l16;
            short8 v0 = *reinterpret_cast<short8*>(&Vs[dr * 64 + q0]);
            short8 v1 = *reinterpret_cast<short8*>(&Vs[dr * 64 + q1]);
            O[ds] = MFMA16(ap0, v0, O[ds]);
            O[ds] = MFMA16(ap1, v1, O[ds]);
        }
        __syncthreads();
    }

    float lr[4];
    #pragma unroll
    for (int r = 0; r < 4; r++) {
        float s = pl[r];
        #pragma unroll
        for (int msk = 1; msk < 16; msk <<= 1) s += __shfl_xor(s, msk);
        lr[r] = s;
    }
    #pragma unroll
    for (int ds = 0; ds < 4; ds++)
        #pragma unroll
        for (int r = 0; r < 4; r++) {
            int q = qbase + quad * 4 + r;
            AVbf[((size_t)q * 2 + b) * 1024 + n * 64 + 16 * ds + l16] =
                f2b(O[ds][r] / lr[r]);
        }
}

// ---------------- out = LN(w + attn_out), f32 ----------------
__global__ __launch_bounds__(256)
void ln_res(const float* __restrict__ ao, const float* __restrict__ w,
            const float* __restrict__ gamma, const float* __restrict__ beta,
            float* __restrict__ out) {
    const int m = blockIdx.x;
    const int t = threadIdx.x;
    __shared__ float red[256];
    float x[4];
    #pragma unroll
    for (int e = 0; e < 4; e++) {
        int c = e * 256 + t;
        x[e] = ao[(size_t)m * DMODEL + c] + w[(size_t)m * DMODEL + c];
    }
    float s = x[0] + x[1] + x[2] + x[3];
    red[t] = s;
    __syncthreads();
    #pragma unroll
    for (int off = 128; off; off >>= 1) {
        if (t < off) red[t] += red[t + off];
        __syncthreads();
    }
    const float mu = red[0] * (1.f / 1024.f);
    __syncthreads();
    float s2 = 0.f;
    #pragma unroll
    for (int e = 0; e < 4; e++) { float dx = x[e] - mu; s2 += dx * dx; }
    red[t] = s2;
    __syncthreads();
    #pragma unroll
    for (int off = 128; off; off >>= 1) {
        if (t < off) red[t] += red[t + off];
        __syncthreads();
    }
    const float rstd = rsqrtf(red[0] * (1.f / 1024.f) + LN_EPS);
    #pragma unroll
    for (int e = 0; e < 4; e++) {
        int c = e * 256 + t;
        out[(size_t)m * DMODEL + c] = (x[e] - mu) * rstd * gamma[c] + beta[c];
    }
}

extern "C" void kernel_launch(void* const* d_in, const int* in_sizes, int n_in,
                              void* d_out, int out_size, void* d_ws, size_t ws_size,
                              hipStream_t stream) {
    const float* w        = (const float*)d_in[0];
    const float* r        = (const float*)d_in[1];
    const float* r_w_bias = (const float*)d_in[2];
    const float* r_r_bias = (const float*)d_in[3];
    const float* mems     = (const float*)d_in[4];
    // d_in[5] attn_mask: deterministic (j <= i+MEMLEN), applied analytically
    const float* W_qkv    = (const float*)d_in[6];
    const float* W_r      = (const float*)d_in[7];
    const float* W_o      = (const float*)d_in[8];
    const float* gamma    = (const float*)d_in[9];
    const float* beta     = (const float*)d_in[10];
    float* out = (float*)d_out;

    // Workspace (~54 MB). attn_out f32 aliases Abf (dead after QKV GEMM).
    bf16* Abf    = (bf16*)d_ws;                    // [4096,1024] cat rows m=j*2+b
    bf16* Wqkvt  = Abf   + (size_t)4096 * 1024;    // [3072,1024]
    bf16* Wrt    = Wqkvt + (size_t)3072 * 1024;    // [1024,1024]
    bf16* Wot    = Wrt   + (size_t)1024 * 1024;    // [1024,1024]
    bf16* rbf    = Wot   + (size_t)1024 * 1024;    // [2048,1024]
    bf16* Qw     = rbf   + (size_t)2048 * 1024;    // [2048,1024] rows i*2+b
    bf16* Qr     = Qw    + (size_t)2048 * 1024;
    bf16* Kb     = Qr    + (size_t)2048 * 1024;    // [4096,1024] rows j*2+b
    bf16* Vt     = Kb    + (size_t)4096 * 1024;    // [2048,2048] rows d*2+b
    bf16* Rk     = Vt    + (size_t)2048 * 2048;    // [2048,1024]
    bf16* AVbf   = Rk    + (size_t)2048 * 1024;    // [2048,1024]
    float* attn_out = (float*)Abf;                 // [2048,1024] f32 (alias)

    dim3 b256(256);
    prep<<<dim3(7424), b256, 0, stream>>>(mems, w, r, W_qkv, W_r, W_o,
                                          Abf, rbf, Wqkvt, Wrt, Wot);
    // QKV GEMM (+ recycled Rk tiles, + direct transposed Vt writes)
    gemm_mfma<<<dim3(32, 24), b256, 0, stream>>>(
        Abf, Wqkvt, rbf, Wrt, 4096, 3072, 1024, 0, r_w_bias, r_r_bias,
        Qw, Qr, Kb, Vt, Rk, nullptr);
    attn_mfma<<<dim3(512), b256, 0, stream>>>(Qw, Qr, Kb, Vt, Rk, AVbf);
    gemm_mfma<<<dim3(16, 8), b256, 0, stream>>>(
        AVbf, Wot, nullptr, nullptr, 2048, 1024, 1024, 2, nullptr, nullptr,
        nullptr, nullptr, nullptr, nullptr, nullptr, attn_out);
    ln_res<<<dim3(QLEN * BSZ), b256, 0, stream>>>(attn_out, w, gamma, beta, out);
}